// Round 1
// baseline (4394.543 us; speedup 1.0000x reference)
//
#include <hip/hip_runtime.h>
#include <math.h>

// Problem constants (derived from reference): F=4, T=12, C=512, HID=256, OUT=12
#define NF 48   // F*T per-node feature block in x / Y
#define TT 12

// ---------------- small prep kernels ----------------

__global__ void k_init_deg(float* __restrict__ deg, int n) {
  int i = blockIdx.x * blockDim.x + threadIdx.x;
  if (i < n) deg[i] = 1.0f;  // self-loop weight
}

__global__ void k_scatter_deg(const int* __restrict__ dst, const float* __restrict__ w,
                              float* __restrict__ deg, int e) {
  int i = blockIdx.x * blockDim.x + threadIdx.x;
  if (i < e) atomicAdd(&deg[dst[i]], w[i]);
}

__global__ void k_dinv(const float* __restrict__ deg, float* __restrict__ dinv, int n) {
  int i = blockIdx.x * blockDim.x + threadIdx.x;
  if (i < n) dinv[i] = rsqrtf(fmaxf(deg[i], 1e-12f));
}

// Y[i,:] = dinv[i]^2 * x[i,:]  (self loop term), full coverage of Y
__global__ void k_initY(const float* __restrict__ x, const float* __restrict__ dinv,
                        float* __restrict__ Y, int n) {
  int idx = blockIdx.x * blockDim.x + threadIdx.x;
  if (idx < n * NF) {
    int i = idx / NF;
    float d = dinv[i];
    Y[idx] = d * d * x[idx];
  }
}

// Y[dst,:] += norm_e * x[src,:]
__global__ void k_scatterY(const int* __restrict__ src, const int* __restrict__ dst,
                           const float* __restrict__ w, const float* __restrict__ dinv,
                           const float* __restrict__ x, float* __restrict__ Y, int e) {
  int i = blockIdx.x * blockDim.x + threadIdx.x;
  if (i >= e) return;
  int s = src[i], d = dst[i];
  float nm = dinv[s] * w[i] * dinv[d];
  const float4* xs = (const float4*)(x + (size_t)s * NF);
  float* yd = Y + (size_t)d * NF;
#pragma unroll
  for (int q = 0; q < NF / 4; q++) {
    float4 v = xs[q];
    atomicAdd(&yd[q * 4 + 0], nm * v.x);
    atomicAdd(&yd[q * 4 + 1], nm * v.y);
    atomicAdd(&yd[q * 4 + 2], nm * v.z);
    atomicAdd(&yd[q * 4 + 3], nm * v.w);
  }
}

// Wzr_bot[k, c'] (k<512, c'<1024): bottom halves of Wz_l | Wr_l concatenated on cols
__global__ void k_build_zrbot(const float* __restrict__ Wzl, const float* __restrict__ Wrl,
                              float* __restrict__ Wzr) {
  int idx = blockIdx.x * blockDim.x + threadIdx.x;
  if (idx >= 512 * 1024) return;
  int k = idx >> 10, c = idx & 1023;
  Wzr[idx] = (c < 512) ? Wzl[(512 + k) * 512 + c] : Wrl[(512 + k) * 512 + (c - 512)];
}

// Weff[f, c] = sum_k Wg[f,k] * Wl_top[k,c];  beff[c] = sum_k bg[k]*Wl_top[k,c] + bl[c]
__global__ void k_build_eff(const float* __restrict__ Wg, const float* __restrict__ Wl,
                            const float* __restrict__ bg, const float* __restrict__ bl,
                            float* __restrict__ Weff, float* __restrict__ beff,
                            int ostride, int ooff) {
  int idx = blockIdx.x * blockDim.x + threadIdx.x;
  if (idx >= 5 * 512) return;
  int r = idx / 512, c = idx % 512;
  float s = 0.f;
  if (r < 4) {
    for (int k = 0; k < 512; k++) s += Wg[r * 512 + k] * Wl[k * 512 + c];
    Weff[r * ostride + ooff + c] = s;
  } else {
    for (int k = 0; k < 512; k++) s += bg[k] * Wl[k * 512 + c];
    beff[ooff + c] = s + bl[c];
  }
}

__global__ void k_softmax_att(const float* __restrict__ att, float* __restrict__ probs) {
  if (blockIdx.x == 0 && threadIdx.x == 0) {
    float m = -1e30f;
    for (int t = 0; t < TT; t++) m = fmaxf(m, att[t]);
    float e[TT], s = 0.f;
    for (int t = 0; t < TT; t++) { e[t] = expf(att[t] - m); s += e[t]; }
    for (int t = 0; t < TT; t++) probs[t] = e[t] / s;
  }
}

__global__ void k_zero(float* __restrict__ p, int n) {
  int i = blockIdx.x * blockDim.x + threadIdx.x;
  if (i < n) p[i] = 0.f;
}

// ---------------- fused GEMM ----------------
// C_tile = A[M,K] @ B[K,Nout], 128x128 tile, 8x8 microtile, BK=16.
// MODE 0 (zr):  A=H.       epi: sigmoid(pre + Y_t@Weff + beff) -> ZR[M,1024]
// MODE 1 (h):   A=H (staging multiplies by r=ZR[:,512+k]).
//               epi: ht=tanh(pre+Y_t@Weff+beff); hn=z*H+(1-z)*ht -> Hn; acc+=p_t*hn
// MODE 2 (head1): A=relu(acc) via staging relu. epi: relu(pre+b1) -> T1[M,256]
template <int MODE>
__global__ __launch_bounds__(256) void k_gemm(
    const float* __restrict__ A, const float* __restrict__ B,
    const float* __restrict__ ZR, const float* __restrict__ Y,
    const float* __restrict__ Weff, const float* __restrict__ beff,
    const float* __restrict__ probs,
    float* __restrict__ O1, float* __restrict__ acc,
    int M, int K, int Nout, int t) {
  __shared__ float As[16][132];  // transposed A tile, padded stride (2-way max conflicts)
  __shared__ float Bs[16][128];
  const int tid = threadIdx.x;
  const int tr = tid >> 4;
  const int tc = tid & 15;
  const int row0 = blockIdx.x * 128;
  const int col0 = blockIdx.y * 128;

  float accr[8][8];
#pragma unroll
  for (int i = 0; i < 8; i++)
#pragma unroll
    for (int j = 0; j < 8; j++) accr[i][j] = 0.f;

  for (int k0 = 0; k0 < K; k0 += 16) {
#pragma unroll
    for (int d = 0; d < 2; d++) {
      int u = tid + d * 256;
      // A tile: 128 rows x 16 k
      int ar = u >> 2;
      int aq = (u & 3) << 2;
      int arg = row0 + ar;
      float4 av = make_float4(0.f, 0.f, 0.f, 0.f);
      if (arg < M) {
        av = *(const float4*)(A + (size_t)arg * K + k0 + aq);
        if constexpr (MODE == 1) {
          float4 rv = *(const float4*)(ZR + (size_t)arg * 1024 + 512 + k0 + aq);
          av.x *= rv.x; av.y *= rv.y; av.z *= rv.z; av.w *= rv.w;
        }
        if constexpr (MODE == 2) {
          av.x = fmaxf(av.x, 0.f); av.y = fmaxf(av.y, 0.f);
          av.z = fmaxf(av.z, 0.f); av.w = fmaxf(av.w, 0.f);
        }
      }
      As[aq + 0][ar] = av.x; As[aq + 1][ar] = av.y;
      As[aq + 2][ar] = av.z; As[aq + 3][ar] = av.w;
      // B tile: 16 rows x 128 cols
      int br = u >> 5;
      int bq = (u & 31) << 2;
      float4 bv = *(const float4*)(B + (size_t)(k0 + br) * Nout + col0 + bq);
      *(float4*)&Bs[br][bq] = bv;
    }
    __syncthreads();
#pragma unroll
    for (int k = 0; k < 16; k++) {
      float4 a0 = *(const float4*)&As[k][tr * 4];
      float4 a1 = *(const float4*)&As[k][64 + tr * 4];
      float4 b0 = *(const float4*)&Bs[k][tc * 4];
      float4 b1 = *(const float4*)&Bs[k][64 + tc * 4];
      float av8[8] = {a0.x, a0.y, a0.z, a0.w, a1.x, a1.y, a1.z, a1.w};
      float bv8[8] = {b0.x, b0.y, b0.z, b0.w, b1.x, b1.y, b1.z, b1.w};
#pragma unroll
      for (int i = 0; i < 8; i++)
#pragma unroll
        for (int j = 0; j < 8; j++) accr[i][j] = fmaf(av8[i], bv8[j], accr[i][j]);
    }
    __syncthreads();
  }

  float pt = 0.f;
  if constexpr (MODE == 1) pt = probs[t];
#pragma unroll
  for (int i = 0; i < 8; i++) {
    int rg = row0 + tr * 4 + (i & 3) + ((i >> 2) << 6);
    if (rg >= M) continue;
    float yv0 = 0.f, yv1 = 0.f, yv2 = 0.f, yv3 = 0.f;
    if constexpr (MODE < 2) {
      const float* yr = Y + (size_t)rg * NF;
      yv0 = yr[0 * TT + t]; yv1 = yr[1 * TT + t];
      yv2 = yr[2 * TT + t]; yv3 = yr[3 * TT + t];
    }
#pragma unroll
    for (int j = 0; j < 8; j++) {
      int cg = col0 + tc * 4 + (j & 3) + ((j >> 2) << 6);
      float pre = accr[i][j] + beff[cg];
      if constexpr (MODE < 2) {
        pre += yv0 * Weff[cg] + yv1 * Weff[Nout + cg] +
               yv2 * Weff[2 * Nout + cg] + yv3 * Weff[3 * Nout + cg];
      }
      if constexpr (MODE == 0) {
        O1[(size_t)rg * 1024 + cg] = 1.f / (1.f + expf(-pre));
      } else if constexpr (MODE == 1) {
        float ht = tanhf(pre);
        float z = ZR[(size_t)rg * 1024 + cg];
        float hold = A[(size_t)rg * 512 + cg];
        float hn = z * hold + (1.f - z) * ht;
        O1[(size_t)rg * 512 + cg] = hn;
        acc[(size_t)rg * 512 + cg] += pt * hn;
      } else {
        O1[(size_t)rg * 256 + cg] = fmaxf(pre, 0.f);
      }
    }
  }
}

// out0[i,c] = relu-free final: T1[i,:] @ W2 + b2   (K=256, OUT=12)
__global__ void k_head2(const float* __restrict__ T1, const float* __restrict__ W2,
                        const float* __restrict__ b2, float* __restrict__ out0, int M) {
  int idx = blockIdx.x * blockDim.x + threadIdx.x;
  if (idx >= M * 12) return;
  int i = idx / 12, c = idx % 12;
  const float* tr = T1 + (size_t)i * 256;
  float s = b2[c];
  for (int k = 0; k < 256; k++) s = fmaf(tr[k], W2[k * 12 + c], s);
  out0[idx] = s;
}

// ---------------- launch ----------------

extern "C" void kernel_launch(void* const* d_in, const int* in_sizes, int n_in,
                              void* d_out, int out_size, void* d_ws, size_t ws_size,
                              hipStream_t stream) {
  const float* x   = (const float*)d_in[0];
  const int*   ei  = (const int*)d_in[1];
  const float* ea  = (const float*)d_in[2];
  const float* att = (const float*)d_in[3];
  const float* Wzg = (const float*)d_in[4];  const float* bzg = (const float*)d_in[5];
  const float* Wzl = (const float*)d_in[6];  const float* bzl = (const float*)d_in[7];
  const float* Wrg = (const float*)d_in[8];  const float* brg = (const float*)d_in[9];
  const float* Wrl = (const float*)d_in[10]; const float* brl = (const float*)d_in[11];
  const float* Whg = (const float*)d_in[12]; const float* bhg = (const float*)d_in[13];
  const float* Whl = (const float*)d_in[14]; const float* bhl = (const float*)d_in[15];
  const float* W1  = (const float*)d_in[16]; const float* b1  = (const float*)d_in[17];
  const float* W2  = (const float*)d_in[18]; const float* b2  = (const float*)d_in[19];

  const int N = in_sizes[0] / NF;
  const int E = in_sizes[1] / 2;
  const int* srcI = ei;
  const int* dstI = ei + E;

  float* out0 = (float*)d_out;              // [N,12]
  float* accO = (float*)d_out + (size_t)N * 12;  // [N,512] = H_accum (output 1)

  char* wp = (char*)d_ws;
  auto carve = [&](size_t bytes) -> float* {
    float* p = (float*)wp;
    wp += (bytes + 255) & ~(size_t)255;
    return p;
  };
  float* deg     = carve((size_t)N * 4);
  float* dinv    = carve((size_t)N * 4);
  float* probs   = carve(64);
  float* Y       = carve((size_t)N * NF * 4);
  float* Wzr     = carve((size_t)512 * 1024 * 4);
  float* Wzr_eff = carve((size_t)4 * 1024 * 4);
  float* bzr_eff = carve((size_t)1024 * 4);
  float* Wh_eff  = carve((size_t)4 * 512 * 4);
  float* bh_eff  = carve((size_t)512 * 4);
  float* Ha      = carve((size_t)N * 512 * 4);
  float* Hb      = carve((size_t)N * 512 * 4);
  float* ZR      = carve((size_t)N * 1024 * 4);
  float* T1      = carve((size_t)N * 256 * 4);
  (void)ws_size; (void)n_in; (void)out_size;

  const int TPB = 256;
  auto cdiv = [](int a, int b) { return (a + b - 1) / b; };

  // graph prep: Y = Ahat @ X (all T at once)
  k_init_deg<<<cdiv(N, TPB), TPB, 0, stream>>>(deg, N);
  k_scatter_deg<<<cdiv(E, TPB), TPB, 0, stream>>>(dstI, ea, deg, E);
  k_dinv<<<cdiv(N, TPB), TPB, 0, stream>>>(deg, dinv, N);
  k_initY<<<cdiv(N * NF, TPB), TPB, 0, stream>>>(x, dinv, Y, N);
  k_scatterY<<<cdiv(E, TPB), TPB, 0, stream>>>(srcI, dstI, ea, dinv, x, Y, E);

  // fold GCN weights through the gate linears
  k_build_zrbot<<<cdiv(512 * 1024, TPB), TPB, 0, stream>>>(Wzl, Wrl, Wzr);
  k_build_eff<<<cdiv(5 * 512, TPB), TPB, 0, stream>>>(Wzg, Wzl, bzg, bzl, Wzr_eff, bzr_eff, 1024, 0);
  k_build_eff<<<cdiv(5 * 512, TPB), TPB, 0, stream>>>(Wrg, Wrl, brg, brl, Wzr_eff, bzr_eff, 1024, 512);
  k_build_eff<<<cdiv(5 * 512, TPB), TPB, 0, stream>>>(Whg, Whl, bhg, bhl, Wh_eff, bh_eff, 512, 0);
  k_softmax_att<<<1, 64, 0, stream>>>(att, probs);

  k_zero<<<cdiv(N * 512, TPB), TPB, 0, stream>>>(Ha, N * 512);
  k_zero<<<cdiv(N * 512, TPB), TPB, 0, stream>>>(accO, N * 512);

  const int gx = cdiv(N, 128);
  float* Hc = Ha;
  float* Hn = Hb;
  for (int t = 0; t < TT; t++) {
    dim3 gzr(gx, 8);
    k_gemm<0><<<gzr, 256, 0, stream>>>(Hc, Wzr, nullptr, Y, Wzr_eff, bzr_eff, probs,
                                       ZR, nullptr, N, 512, 1024, t);
    dim3 gh(gx, 4);
    k_gemm<1><<<gh, 256, 0, stream>>>(Hc, Whl + 512 * 512, ZR, Y, Wh_eff, bh_eff, probs,
                                      Hn, accO, N, 512, 512, t);
    float* tmp = Hc; Hc = Hn; Hn = tmp;
  }

  // head: relu(acc) @ W1 + b1 -> relu -> T1 ; T1 @ W2 + b2 -> out0
  dim3 g1(gx, 2);
  k_gemm<2><<<g1, 256, 0, stream>>>(accO, W1, nullptr, nullptr, nullptr, b1, nullptr,
                                    T1, nullptr, N, 512, 256, 0);
  k_head2<<<cdiv(N * 12, TPB), TPB, 0, stream>>>(T1, W2, b2, out0, N);
}

// Round 3
// 1622.469 us; speedup vs baseline: 2.7086x; 2.7086x over previous
//
#include <hip/hip_runtime.h>
#include <math.h>

// F=4, T=12, C=512, HID=256, OUT=12
#define NF 48
#define TT 12

typedef __bf16 v8bf __attribute__((ext_vector_type(8)));
typedef float v4f __attribute__((ext_vector_type(4)));

// ---------------- small prep kernels ----------------

__global__ void k_init_deg(float* __restrict__ deg, int n) {
  int i = blockIdx.x * blockDim.x + threadIdx.x;
  if (i < n) deg[i] = 1.0f;
}

__global__ void k_scatter_deg(const int* __restrict__ dst, const float* __restrict__ w,
                              float* __restrict__ deg, int e) {
  int i = blockIdx.x * blockDim.x + threadIdx.x;
  if (i < e) atomicAdd(&deg[dst[i]], w[i]);
}

__global__ void k_dinv(const float* __restrict__ deg, float* __restrict__ dinv, int n) {
  int i = blockIdx.x * blockDim.x + threadIdx.x;
  if (i < n) dinv[i] = rsqrtf(fmaxf(deg[i], 1e-12f));
}

__global__ void k_zero(float* __restrict__ p, int n) {
  int i = blockIdx.x * blockDim.x + threadIdx.x;
  if (i < n) p[i] = 0.f;
}

__global__ void k_zeroi(int* __restrict__ p, int n) {
  int i = blockIdx.x * blockDim.x + threadIdx.x;
  if (i < n) p[i] = 0;
}

// ---------------- CSR build (by dst) ----------------

__global__ void k_count(const int* __restrict__ dst, int* __restrict__ cnt, int e) {
  int i = blockIdx.x * blockDim.x + threadIdx.x;
  if (i < e) atomicAdd(&cnt[dst[i]], 1);
}

// single-block exclusive scan over n counts -> offs[0..n]
__global__ void k_scan(const int* __restrict__ cnt, int* __restrict__ offs, int n) {
  __shared__ int s[1024];
  __shared__ int carry;
  int tid = threadIdx.x;
  if (tid == 0) carry = 0;
  __syncthreads();
  for (int base = 0; base < n; base += 1024) {
    int v = (base + tid < n) ? cnt[base + tid] : 0;
    s[tid] = v;
    __syncthreads();
    for (int off = 1; off < 1024; off <<= 1) {
      int t = 0;
      if (tid >= off) t = s[tid - off];
      __syncthreads();
      s[tid] += t;
      __syncthreads();
    }
    if (base + tid < n) offs[base + tid] = carry + s[tid] - v;
    __syncthreads();
    if (tid == 0) carry += s[1023];
    __syncthreads();
  }
  if (tid == 0) offs[n] = carry;
}

__global__ void k_place(const int* __restrict__ src, const int* __restrict__ dst,
                        const float* __restrict__ w, const int* __restrict__ offs,
                        int* __restrict__ fill, int* __restrict__ csrc,
                        float* __restrict__ cw, int e) {
  int i = blockIdx.x * blockDim.x + threadIdx.x;
  if (i >= e) return;
  int d = dst[i];
  int p = offs[d] + atomicAdd(&fill[d], 1);
  csrc[p] = src[i];
  cw[p] = w[i];
}

// Y[n, q*4..] = dinv[n] * ( dinv[n]*x[n,q*4..] + sum_e dinv[src]*w*x[src,q*4..] )
__global__ void k_gather(const int* __restrict__ offs, const int* __restrict__ csrc,
                         const float* __restrict__ cw, const float* __restrict__ dinv,
                         const float* __restrict__ x, float* __restrict__ Y, int n) {
  int tg = blockIdx.x * blockDim.x + threadIdx.x;
  if (tg >= n * 12) return;
  int i = tg / 12, q = tg % 12;
  float di = dinv[i];
  const float4* x4 = (const float4*)x;
  float4 sv = x4[(size_t)i * 12 + q];
  float ax = di * sv.x, ay = di * sv.y, az = di * sv.z, aw = di * sv.w;
  int e1 = offs[i + 1];
  for (int e = offs[i]; e < e1; e++) {
    int s = csrc[e];
    float wv = cw[e] * dinv[s];
    float4 xv = x4[(size_t)s * 12 + q];
    ax = fmaf(wv, xv.x, ax); ay = fmaf(wv, xv.y, ay);
    az = fmaf(wv, xv.z, az); aw = fmaf(wv, xv.w, aw);
  }
  float4 o = make_float4(di * ax, di * ay, di * az, di * aw);
  ((float4*)Y)[(size_t)i * 12 + q] = o;
}

// ---------------- weight prep ----------------

// WzrT[c,k] bf16 (c<1024, k<512): bottom halves of Wz_l | Wr_l, transposed
__global__ void k_t_zr(const float* __restrict__ Wzl, const float* __restrict__ Wrl,
                       __bf16* __restrict__ WT) {
  int idx = blockIdx.x * blockDim.x + threadIdx.x;
  if (idx >= 1024 * 512) return;
  int c = idx >> 9, k = idx & 511;
  float v = (c < 512) ? Wzl[(512 + k) * 512 + c] : Wrl[(512 + k) * 512 + (c - 512)];
  WT[idx] = (__bf16)v;
}

__global__ void k_t_h(const float* __restrict__ Whl, __bf16* __restrict__ WT) {
  int idx = blockIdx.x * blockDim.x + threadIdx.x;
  if (idx >= 512 * 512) return;
  int c = idx >> 9, k = idx & 511;
  WT[idx] = (__bf16)Whl[(512 + k) * 512 + c];
}

__global__ void k_t_1(const float* __restrict__ W1, __bf16* __restrict__ WT) {
  int idx = blockIdx.x * blockDim.x + threadIdx.x;
  if (idx >= 256 * 512) return;
  int c = idx >> 9, k = idx & 511;
  WT[idx] = (__bf16)W1[k * 256 + c];
}

// Weff[f,c] = sum_k Wg[f,k]*Wl_top[k,c]; beff[c] = sum_k bg[k]*Wl_top[k,c] + bl[c]
__global__ void k_build_eff(const float* __restrict__ Wg, const float* __restrict__ Wl,
                            const float* __restrict__ bg, const float* __restrict__ bl,
                            float* __restrict__ Weff, float* __restrict__ beff,
                            int ostride, int ooff) {
  int idx = blockIdx.x * blockDim.x + threadIdx.x;
  if (idx >= 5 * 512) return;
  int r = idx / 512, c = idx % 512;
  float s = 0.f;
  if (r < 4) {
    for (int k = 0; k < 512; k++) s += Wg[r * 512 + k] * Wl[k * 512 + c];
    Weff[r * ostride + ooff + c] = s;
  } else {
    for (int k = 0; k < 512; k++) s += bg[k] * Wl[k * 512 + c];
    beff[ooff + c] = s + bl[c];
  }
}

__global__ void k_softmax_att(const float* __restrict__ att, float* __restrict__ probs) {
  if (blockIdx.x == 0 && threadIdx.x == 0) {
    float m = -1e30f;
    for (int t = 0; t < TT; t++) m = fmaxf(m, att[t]);
    float e[TT], s = 0.f;
    for (int t = 0; t < TT; t++) { e[t] = expf(att[t] - m); s += e[t]; }
    for (int t = 0; t < TT; t++) probs[t] = e[t] / s;
  }
}

// ---------------- MFMA GEMM ----------------
// C = A[M,512] @ Bt^T  (Bt is [Nout,512] bf16, row-major over output cols)
// 128x128 block tile, 4 waves in 2x2, each wave 64x64 (4x4 of 16x16x32 mfma), BK=32.
// MODE 0: A=H fp32->bf16.        epi: sigmoid(pre + Y_t@Weff + beff) -> ZR[M,1024]
// MODE 1: A=(H*r) fp32->bf16.    epi: ht=tanh(...); hn=z*H+(1-z)*ht -> O1; acc+=p_t*hn
// MODE 2: A=relu(accO) ->bf16.   epi: relu(pre+b1) -> T1[M,256]
template <int MODE>
__global__ __launch_bounds__(256, 2) void k_mm(
    const float* __restrict__ A, const __bf16* __restrict__ Bt,
    const float* __restrict__ ZR, const float* __restrict__ Y,
    const float* __restrict__ Weff, const float* __restrict__ beff,
    const float* __restrict__ probs,
    float* __restrict__ O1, float* __restrict__ acc,
    int M, int t) {
  constexpr int Nout = (MODE == 0) ? 1024 : (MODE == 1 ? 512 : 256);
  constexpr int LDA = 40;  // padded LDS row stride (bf16 elems): 80B, 16B-aligned rows
  __shared__ __bf16 sA[128 * LDA];
  __shared__ __bf16 sB[128 * LDA];
  const int tid = threadIdx.x;
  const int row0 = blockIdx.x * 128;
  const int col0 = blockIdx.y * 128;
  const int w = tid >> 6, lane = tid & 63;
  const int wr = (w >> 1) * 64, wc = (w & 1) * 64;
  const int lm = lane & 15, quad = lane >> 4;

  v4f acc4[4][4];
#pragma unroll
  for (int i = 0; i < 4; i++)
#pragma unroll
    for (int j = 0; j < 4; j++) acc4[i][j] = (v4f){0.f, 0.f, 0.f, 0.f};

  const int sr = tid >> 1;          // staging row within tile
  const int sh = (tid & 1) * 16;    // staging k-offset (elements)
  const int argA = row0 + sr;
  const float* Arow = A + (size_t)argA * 512;
  const float* Rrow = ZR + (size_t)argA * 1024 + 512;
  const __bf16* Brow = Bt + (size_t)(col0 + sr) * 512;
  __bf16* sAw = &sA[sr * LDA + sh];
  __bf16* sBw = &sB[sr * LDA + sh];

  for (int k0 = 0; k0 < 512; k0 += 32) {
    v8bf pa[2];
    if (argA < M) {
#pragma unroll
      for (int g = 0; g < 2; g++) {
        float4 x0 = *(const float4*)(Arow + k0 + sh + g * 8);
        float4 x1 = *(const float4*)(Arow + k0 + sh + g * 8 + 4);
        if constexpr (MODE == 1) {
          float4 r0 = *(const float4*)(Rrow + k0 + sh + g * 8);
          float4 r1 = *(const float4*)(Rrow + k0 + sh + g * 8 + 4);
          x0.x *= r0.x; x0.y *= r0.y; x0.z *= r0.z; x0.w *= r0.w;
          x1.x *= r1.x; x1.y *= r1.y; x1.z *= r1.z; x1.w *= r1.w;
        }
        if constexpr (MODE == 2) {
          x0.x = fmaxf(x0.x, 0.f); x0.y = fmaxf(x0.y, 0.f);
          x0.z = fmaxf(x0.z, 0.f); x0.w = fmaxf(x0.w, 0.f);
          x1.x = fmaxf(x1.x, 0.f); x1.y = fmaxf(x1.y, 0.f);
          x1.z = fmaxf(x1.z, 0.f); x1.w = fmaxf(x1.w, 0.f);
        }
        v8bf o;
        o[0] = (__bf16)x0.x; o[1] = (__bf16)x0.y; o[2] = (__bf16)x0.z; o[3] = (__bf16)x0.w;
        o[4] = (__bf16)x1.x; o[5] = (__bf16)x1.y; o[6] = (__bf16)x1.z; o[7] = (__bf16)x1.w;
        pa[g] = o;
      }
    } else {
      v8bf z;
#pragma unroll
      for (int j = 0; j < 8; j++) z[j] = (__bf16)0.f;
      pa[0] = z; pa[1] = z;
    }
    uint4 pb0 = *(const uint4*)(Brow + k0 + sh);
    uint4 pb1 = *(const uint4*)(Brow + k0 + sh + 8);
    __syncthreads();
    *(v8bf*)(sAw) = pa[0];
    *(v8bf*)(sAw + 8) = pa[1];
    *(uint4*)(sBw) = pb0;
    *(uint4*)(sBw + 8) = pb1;
    __syncthreads();

    v8bf af[4], bf[4];
#pragma unroll
    for (int mi = 0; mi < 4; mi++)
      af[mi] = *(const v8bf*)(&sA[(wr + mi * 16 + lm) * LDA + quad * 8]);
#pragma unroll
    for (int ni = 0; ni < 4; ni++)
      bf[ni] = *(const v8bf*)(&sB[(wc + ni * 16 + lm) * LDA + quad * 8]);
#pragma unroll
    for (int mi = 0; mi < 4; mi++)
#pragma unroll
      for (int ni = 0; ni < 4; ni++)
        acc4[mi][ni] = __builtin_amdgcn_mfma_f32_16x16x32_bf16(af[mi], bf[ni], acc4[mi][ni], 0, 0, 0);
  }

  float pt = (MODE == 1) ? probs[t] : 0.f;
#pragma unroll
  for (int mi = 0; mi < 4; mi++) {
#pragma unroll
    for (int r = 0; r < 4; r++) {
      int rg = row0 + wr + mi * 16 + quad * 4 + r;
      if (rg >= M) continue;
      float yv0 = 0.f, yv1 = 0.f, yv2 = 0.f, yv3 = 0.f;
      if constexpr (MODE < 2) {
        const float* yr = Y + (size_t)rg * NF;
        yv0 = yr[0 * TT + t]; yv1 = yr[1 * TT + t];
        yv2 = yr[2 * TT + t]; yv3 = yr[3 * TT + t];
      }
#pragma unroll
      for (int ni = 0; ni < 4; ni++) {
        int cg = col0 + wc + ni * 16 + lm;
        float pre = acc4[mi][ni][r] + beff[cg];
        if constexpr (MODE < 2) {
          pre += yv0 * Weff[cg] + yv1 * Weff[Nout + cg] +
                 yv2 * Weff[2 * Nout + cg] + yv3 * Weff[3 * Nout + cg];
        }
        if constexpr (MODE == 0) {
          O1[(size_t)rg * 1024 + cg] = 1.f / (1.f + expf(-pre));
        } else if constexpr (MODE == 1) {
          float ht = tanhf(pre);
          float z = ZR[(size_t)rg * 1024 + cg];
          float hold = A[(size_t)rg * 512 + cg];
          float hn = z * hold + (1.f - z) * ht;
          O1[(size_t)rg * 512 + cg] = hn;
          acc[(size_t)rg * 512 + cg] += pt * hn;
        } else {
          O1[(size_t)rg * 256 + cg] = fmaxf(pre, 0.f);
        }
      }
    }
  }
}

__global__ void k_head2(const float* __restrict__ T1, const float* __restrict__ W2,
                        const float* __restrict__ b2, float* __restrict__ out0, int M) {
  int idx = blockIdx.x * blockDim.x + threadIdx.x;
  if (idx >= M * 12) return;
  int i = idx / 12, c = idx % 12;
  const float* tr = T1 + (size_t)i * 256;
  float s = b2[c];
  for (int k = 0; k < 256; k++) s = fmaf(tr[k], W2[k * 12 + c], s);
  out0[idx] = s;
}

// ---------------- launch ----------------

extern "C" void kernel_launch(void* const* d_in, const int* in_sizes, int n_in,
                              void* d_out, int out_size, void* d_ws, size_t ws_size,
                              hipStream_t stream) {
  const float* x   = (const float*)d_in[0];
  const int*   ei  = (const int*)d_in[1];
  const float* ea  = (const float*)d_in[2];
  const float* att = (const float*)d_in[3];
  const float* Wzg = (const float*)d_in[4];  const float* bzg = (const float*)d_in[5];
  const float* Wzl = (const float*)d_in[6];  const float* bzl = (const float*)d_in[7];
  const float* Wrg = (const float*)d_in[8];  const float* brg = (const float*)d_in[9];
  const float* Wrl = (const float*)d_in[10]; const float* brl = (const float*)d_in[11];
  const float* Whg = (const float*)d_in[12]; const float* bhg = (const float*)d_in[13];
  const float* Whl = (const float*)d_in[14]; const float* bhl = (const float*)d_in[15];
  const float* W1  = (const float*)d_in[16]; const float* b1  = (const float*)d_in[17];
  const float* W2  = (const float*)d_in[18]; const float* b2  = (const float*)d_in[19];

  const int N = in_sizes[0] / NF;
  const int E = in_sizes[1] / 2;
  const int* srcI = ei;
  const int* dstI = ei + E;

  float* out0 = (float*)d_out;                   // [N,12]
  float* accO = (float*)d_out + (size_t)N * 12;  // [N,512] = H_accum (output 1)

  char* wp = (char*)d_ws;
  auto carve = [&](size_t bytes) -> void* {
    void* p = (void*)wp;
    wp += (bytes + 255) & ~(size_t)255;
    return p;
  };
  float*  deg     = (float*)carve((size_t)N * 4);
  float*  dinv    = (float*)carve((size_t)N * 4);
  float*  probs   = (float*)carve(64);
  float*  Y       = (float*)carve((size_t)N * NF * 4);
  __bf16* WzrT    = (__bf16*)carve((size_t)1024 * 512 * 2);
  __bf16* WhT     = (__bf16*)carve((size_t)512 * 512 * 2);
  __bf16* W1T     = (__bf16*)carve((size_t)256 * 512 * 2);
  float*  Wzr_eff = (float*)carve((size_t)4 * 1024 * 4);
  float*  bzr_eff = (float*)carve((size_t)1024 * 4);
  float*  Wh_eff  = (float*)carve((size_t)4 * 512 * 4);
  float*  bh_eff  = (float*)carve((size_t)512 * 4);
  float*  Ha      = (float*)carve((size_t)N * 512 * 4);
  float*  Hb      = (float*)carve((size_t)N * 512 * 4);
  float*  ZR      = (float*)carve((size_t)N * 1024 * 4);
  float*  T1      = (float*)carve((size_t)N * 256 * 4);
  int*    cnt     = (int*)carve((size_t)2 * N * 4);  // cnt[N] + fill[N] contiguous
  int*    fill    = cnt + N;
  int*    offs    = (int*)carve((size_t)(N + 1) * 4);
  int*    csrc    = (int*)carve((size_t)E * 4);
  float*  cw      = (float*)carve((size_t)E * 4);
  (void)ws_size; (void)n_in; (void)out_size;

  const int TPB = 256;
  auto cdiv = [](int a, int b) { return (a + b - 1) / b; };

  // degree + normalization
  k_init_deg<<<cdiv(N, TPB), TPB, 0, stream>>>(deg, N);
  k_scatter_deg<<<cdiv(E, TPB), TPB, 0, stream>>>(dstI, ea, deg, E);
  k_dinv<<<cdiv(N, TPB), TPB, 0, stream>>>(deg, dinv, N);

  // CSR by dst, then gather Y = Ahat @ X  (all T at once, 48 feat cols)
  k_zeroi<<<cdiv(2 * N, TPB), TPB, 0, stream>>>(cnt, 2 * N);  // zeroes cnt AND fill
  k_count<<<cdiv(E, TPB), TPB, 0, stream>>>(dstI, cnt, E);
  k_scan<<<1, 1024, 0, stream>>>(cnt, offs, N);
  k_place<<<cdiv(E, TPB), TPB, 0, stream>>>(srcI, dstI, ea, offs, fill, csrc, cw, E);
  k_gather<<<cdiv(N * 12, TPB), TPB, 0, stream>>>(offs, csrc, cw, dinv, x, Y, N);

  // fold GCN weights through gate linears; bf16-transpose the big weights
  k_t_zr<<<cdiv(1024 * 512, TPB), TPB, 0, stream>>>(Wzl, Wrl, WzrT);
  k_t_h<<<cdiv(512 * 512, TPB), TPB, 0, stream>>>(Whl, WhT);
  k_t_1<<<cdiv(256 * 512, TPB), TPB, 0, stream>>>(W1, W1T);
  k_build_eff<<<cdiv(5 * 512, TPB), TPB, 0, stream>>>(Wzg, Wzl, bzg, bzl, Wzr_eff, bzr_eff, 1024, 0);
  k_build_eff<<<cdiv(5 * 512, TPB), TPB, 0, stream>>>(Wrg, Wrl, brg, brl, Wzr_eff, bzr_eff, 1024, 512);
  k_build_eff<<<cdiv(5 * 512, TPB), TPB, 0, stream>>>(Whg, Whl, bhg, bhl, Wh_eff, bh_eff, 512, 0);
  k_softmax_att<<<1, 64, 0, stream>>>(att, probs);

  k_zero<<<cdiv(N * 512, TPB), TPB, 0, stream>>>(Ha, N * 512);
  k_zero<<<cdiv(N * 512, TPB), TPB, 0, stream>>>(accO, N * 512);

  const int gx = cdiv(N, 128);
  float* Hc = Ha;
  float* Hn = Hb;
  for (int t = 0; t < TT; t++) {
    dim3 gzr(gx, 8);
    k_mm<0><<<gzr, 256, 0, stream>>>(Hc, WzrT, nullptr, Y, Wzr_eff, bzr_eff, probs,
                                     ZR, nullptr, N, t);
    dim3 gh(gx, 4);
    k_mm<1><<<gh, 256, 0, stream>>>(Hc, WhT, ZR, Y, Wh_eff, bh_eff, probs,
                                    Hn, accO, N, t);
    float* tmp = Hc; Hc = Hn; Hn = tmp;
  }

  dim3 g1(gx, 2);
  k_mm<2><<<g1, 256, 0, stream>>>(accO, W1T, nullptr, nullptr, nullptr, b1, nullptr,
                                  T1, nullptr, N, 0);
  k_head2<<<cdiv(N * 12, TPB), TPB, 0, stream>>>(T1, W2, b2, out0, N);
}